// Round 7
// baseline (265.535 us; speedup 1.0000x reference)
//
#include <hip/hip_runtime.h>
#include <hip/hip_bf16.h>

// Problem constants
#define HW_   784          // 28*28 locations
#define C_IN  256
#define BS    64
#define OC_   64
#define D_TOT 1024         // OC*4*4
#define OH_   31
#define OW_   31

typedef __attribute__((ext_vector_type(8))) _Float16 half8;   // MFMA f16 A/B frag (4 VGPR)
typedef __attribute__((ext_vector_type(4))) _Float16 half4;
typedef __attribute__((ext_vector_type(2))) __fp16   fp16x2;  // cvt_pkrtz result type
typedef __attribute__((ext_vector_type(4))) float    f32x4;   // MFMA C/D frag
typedef __attribute__((ext_vector_type(4))) float    fl4;
typedef __attribute__((ext_vector_type(4))) int      int4v;

union H8 { half8 v; fp16x2 h2[4]; };
union H4 { half4 v; fp16x2 h2[2]; };

// ---------------------------------------------------------------------------
// Kernel 0: pack x[b, c, l] (fp32, l contiguous) -> xp[l][b][c] (fp16, c contiguous)
// x read once -> non-temporal; xp kept cacheable (reused by gemm blocks).
// ---------------------------------------------------------------------------
__global__ __launch_bounds__(256) void pack_x(const float* __restrict__ x,
                                              _Float16* __restrict__ xp) {
    const int b  = blockIdx.x;
    const int c0 = blockIdx.y * 32;
    const int l0 = blockIdx.z * 112;
    const int t  = threadIdx.x;

    __shared__ _Float16 tile[32][114];   // +2 pad -> conflict-free transpose reads

    for (int e = t; e < 32 * 112; e += 256) {
        int cl = e / 112, ll = e % 112;
        float v = __builtin_nontemporal_load(
            x + (size_t)b * (C_IN * HW_) + (size_t)(c0 + cl) * HW_ + (l0 + ll));
        tile[cl][ll] = (_Float16)v;
    }
    __syncthreads();

    for (int e = t; e < 112 * 32; e += 256) {
        int ll = e >> 5, cl = e & 31;
        xp[(size_t)(l0 + ll) * (BS * C_IN) + b * C_IN + (c0 + cl)] = tile[cl][ll];
    }
}

// ---------------------------------------------------------------------------
// Kernel 1: per (location l, 512-wide d-chunk) GEMM  [64b x 256c] @ [256c x 512d]
// 512 threads = 8 waves; wave w owns d-range [chunk*512 + w*64, +64).
// Permuted MFMA column mapping: instance n, col ln  <->  d = dbase + 4*ln + n.
// Lane's B frag = 8 k-rows x 4 contiguous d -> 8 coalesced NON-TEMPORAL dwordx4
// per k-step, fp32->fp16 via packed cvt_pkrtz. No W LDS, no K-loop barriers,
// 2-deep register prefetch. A (x, fp16) staged once in LDS (XOR-swizzled).
// Epilogue: DIRECT half4 NT stores from acc (d-contiguous per lane ->
// 128B-contiguous runs per 16-lane group). No LDS transpose, no barriers.
// ---------------------------------------------------------------------------
__global__ __launch_bounds__(512) void lc_gemm(const _Float16* __restrict__ xp,
                                               const float* __restrict__ W,
                                               _Float16* __restrict__ patches) {
    // XCD-aware swizzle: nwg = 1568 = 8 * 196; 2 chunks of one l stay on one XCD
    const int wg    = blockIdx.x;
    const int lcid  = (wg & 7) * 196 + (wg >> 3);
    const int l     = lcid >> 1;
    const int chunk = lcid & 1;

    const int t     = threadIdx.x;
    const int wave  = t >> 6;          // 0..7
    const int lane  = t & 63;
    const int g     = lane >> 4;       // 0..3  (k-group)
    const int ln    = lane & 15;       // row/col within fragment

    __shared__ __attribute__((aligned(16))) char lds[32 * 1024];

    // ---- stage A tile [64 b][256 c] fp16 (row = 512 B, XOR swizzle (row&7)<<4) ----
    {
        const int4v* src = (const int4v*)(xp + (size_t)l * (BS * C_IN));
        #pragma unroll
        for (int it = 0; it < 4; ++it) {
            int ch  = t + it * 512;        // 16B granule id, 0..2047
            int row = ch >> 5;
            int col = ch & 31;
            int4v v = src[ch];
            *(int4v*)(lds + row * 512 + ((col * 16) ^ ((row & 7) << 4))) = v;
        }
    }
    __syncthreads();

    // this thread's W base: k-row (g*8), d-quad (chunk*512 + wave*64 + 4*ln)
    const float* Wb = W + (size_t)l * (C_IN * D_TOT) + chunk * 512 + wave * 64 + 4 * ln;

    fl4 wA[8], wB[8];
    #pragma unroll
    for (int r = 0; r < 8; ++r)
        wA[r] = __builtin_nontemporal_load((const fl4*)(Wb + (size_t)(g * 8 + r) * D_TOT));
    #pragma unroll
    for (int r = 0; r < 8; ++r)
        wB[r] = __builtin_nontemporal_load((const fl4*)(Wb + (size_t)(32 + g * 8 + r) * D_TOT));

    f32x4 acc[4][4];
    #pragma unroll
    for (int m = 0; m < 4; ++m)
        #pragma unroll
        for (int n = 0; n < 4; ++n)
            acc[m][n] = (f32x4){0.f, 0.f, 0.f, 0.f};

    #pragma unroll
    for (int s = 0; s < 8; s += 2) {
        // ---------- even substep: consume wA (k0 = s*32), prefetch s+2 ----------
        {
            H8 bfr[4];
            #pragma unroll
            for (int n = 0; n < 4; ++n)
                #pragma unroll
                for (int j = 0; j < 4; ++j)
                    bfr[n].h2[j] = __builtin_amdgcn_cvt_pkrtz(wA[2 * j][n], wA[2 * j + 1][n]);

            if (s + 2 < 8) {
                #pragma unroll
                for (int r = 0; r < 8; ++r)
                    wA[r] = __builtin_nontemporal_load(
                        (const fl4*)(Wb + (size_t)((s + 2) * 32 + g * 8 + r) * D_TOT));
            }

            const int k0 = s * 32;
            half8 af[4];
            #pragma unroll
            for (int m = 0; m < 4; ++m) {
                int row = 16 * m + ln;
                af[m] = *(const half8*)(lds + row * 512 +
                                        ((((k0 + g * 8) << 1)) ^ ((row & 7) << 4)));
            }
            #pragma unroll
            for (int m = 0; m < 4; ++m)
                #pragma unroll
                for (int n = 0; n < 4; ++n)
                    acc[m][n] = __builtin_amdgcn_mfma_f32_16x16x32_f16(af[m], bfr[n].v,
                                                                       acc[m][n], 0, 0, 0);
        }
        // ---------- odd substep: consume wB (k0 = (s+1)*32), prefetch s+3 ----------
        {
            H8 bfr[4];
            #pragma unroll
            for (int n = 0; n < 4; ++n)
                #pragma unroll
                for (int j = 0; j < 4; ++j)
                    bfr[n].h2[j] = __builtin_amdgcn_cvt_pkrtz(wB[2 * j][n], wB[2 * j + 1][n]);

            if (s + 3 < 8) {
                #pragma unroll
                for (int r = 0; r < 8; ++r)
                    wB[r] = __builtin_nontemporal_load(
                        (const fl4*)(Wb + (size_t)((s + 3) * 32 + g * 8 + r) * D_TOT));
            }

            const int k0 = (s + 1) * 32;
            half8 af[4];
            #pragma unroll
            for (int m = 0; m < 4; ++m) {
                int row = 16 * m + ln;
                af[m] = *(const half8*)(lds + row * 512 +
                                        ((((k0 + g * 8) << 1)) ^ ((row & 7) << 4)));
            }
            #pragma unroll
            for (int m = 0; m < 4; ++m)
                #pragma unroll
                for (int n = 0; n < 4; ++n)
                    acc[m][n] = __builtin_amdgcn_mfma_f32_16x16x32_f16(af[m], bfr[n].v,
                                                                       acc[m][n], 0, 0, 0);
        }
    }

    // ---- epilogue: direct NT stores. Lane's (m,r) quad = d-contiguous half4 at
    //      patches[l][b=16m+4g+r][chunk*512 + wave*64 + 4*ln .. +3].
    //      16-lane group (fixed g) covers 64 consecutive d = 128B runs. ----
    _Float16* pl = patches + (size_t)l * (BS * D_TOT) + chunk * 512 + wave * 64 + 4 * ln;
    #pragma unroll
    for (int m = 0; m < 4; ++m) {
        #pragma unroll
        for (int r = 0; r < 4; ++r) {
            int b = 16 * m + 4 * g + r;
            H4 hq;
            hq.h2[0] = __builtin_amdgcn_cvt_pkrtz(acc[m][0][r], acc[m][1][r]);
            hq.h2[1] = __builtin_amdgcn_cvt_pkrtz(acc[m][2][r], acc[m][3][r]);
            __builtin_nontemporal_store(hq.v, (half4*)(pl + (size_t)b * D_TOT));
        }
    }
}

// ---------------------------------------------------------------------------
// Kernel 2: fold (overlap-add) gather — no atomics, every patch read once.
// Block = (b, oh-group of 4). Thread = (oc = t>>2, ww = t&3) owns ow = ww*8..+7.
// patches reads stay CACHED (line reuse across di-loop in L2). out stores NT.
// ---------------------------------------------------------------------------
__global__ __launch_bounds__(256) void fold_k(const _Float16* __restrict__ patches,
                                              float* __restrict__ out) {
    const int b   = blockIdx.x;     // 0..63
    const int oh0 = blockIdx.y * 4; // 0,4,...,28
    const int t   = threadIdx.x;
    const int oc  = t >> 2;
    const int ww  = t & 3;
    const int wb  = ww * 8;

    float acc[4][8];
    #pragma unroll
    for (int a = 0; a < 4; ++a)
        #pragma unroll
        for (int o = 0; o < 8; ++o) acc[a][o] = 0.f;

    const size_t pboc = (size_t)b * D_TOT + (size_t)oc * 16;

    #pragma unroll
    for (int a = 0; a < 4; ++a) {
        const int oh = oh0 + a;
        if (oh > 30) continue;             // uniform branch (oh0 wave-uniform)
        #pragma unroll
        for (int di = 0; di < 4; ++di) {
            const int r = oh - di;
            if (r < 0 || r >= 28) continue;
            #pragma unroll
            for (int k = 0; k < 11; ++k) {
                const int wp = wb - 3 + k;
                if (wp < 0 || wp >= 28) continue;
                const int l = r * 28 + wp;
                half4 v = *(const half4*)(patches + (size_t)l * (BS * D_TOT) + pboc + di * 4);
                #pragma unroll
                for (int dj = 0; dj < 4; ++dj) {
                    const int o = (k - 3) + dj;        // = wp + dj - wb, compile-time
                    if (o < 0 || o >= 8) continue;
                    if (wb + o <= 30)
                        acc[a][o] += (float)v[dj];
                }
            }
        }
    }

    #pragma unroll
    for (int a = 0; a < 4; ++a) {
        const int oh = oh0 + a;
        if (oh > 30) continue;
        float* op = out + (((size_t)b * OC_ + oc) * OH_ + oh) * OW_ + wb;
        #pragma unroll
        for (int o = 0; o < 8; ++o) {
            if (wb + o <= 30) __builtin_nontemporal_store(acc[a][o], op + o);
        }
    }
}

// ---------------------------------------------------------------------------
extern "C" void kernel_launch(void* const* d_in, const int* in_sizes, int n_in,
                              void* d_out, int out_size, void* d_ws, size_t ws_size,
                              hipStream_t stream) {
    const float* x = (const float*)d_in[0];
    const float* W = (const float*)d_in[1];
    float* out     = (float*)d_out;

    _Float16* xp      = (_Float16*)d_ws;                              // 25.7 MB
    _Float16* patches = (_Float16*)((char*)d_ws + 25690112);          // 102.8 MB

    pack_x<<<dim3(64, 8, 7), 256, 0, stream>>>(x, xp);
    lc_gemm<<<dim3(HW_ * 2), 512, 0, stream>>>(xp, W, patches);
    fold_k<<<dim3(64, 8), 256, 0, stream>>>(patches, out);
}

// Round 8
// 247.440 us; speedup vs baseline: 1.0731x; 1.0731x over previous
//
#include <hip/hip_runtime.h>
#include <hip/hip_bf16.h>

// Problem constants
#define HW_   784          // 28*28 locations
#define C_IN  256
#define BS    64
#define OC_   64
#define D_TOT 1024         // OC*4*4
#define OH_   31
#define OW_   31

typedef __attribute__((ext_vector_type(8))) _Float16 half8;   // MFMA f16 A/B frag (4 VGPR)
typedef __attribute__((ext_vector_type(4))) _Float16 half4;
typedef __attribute__((ext_vector_type(2))) __fp16   fp16x2;  // cvt_pkrtz result type
typedef __attribute__((ext_vector_type(4))) float    f32x4;   // MFMA C/D frag
typedef __attribute__((ext_vector_type(4))) float    fl4;
typedef __attribute__((ext_vector_type(4))) int      int4v;

union H8 { half8 v; fp16x2 h2[4]; };

// ---------------------------------------------------------------------------
// Kernel 0: pack x[b, c, l] (fp32, l contiguous) -> xp[l][b][c] (fp16, c contiguous)
// x read once -> non-temporal; xp kept cacheable (reused by gemm blocks).
// ---------------------------------------------------------------------------
__global__ __launch_bounds__(256) void pack_x(const float* __restrict__ x,
                                              _Float16* __restrict__ xp) {
    const int b  = blockIdx.x;
    const int c0 = blockIdx.y * 32;
    const int l0 = blockIdx.z * 112;
    const int t  = threadIdx.x;

    __shared__ _Float16 tile[32][114];   // +2 pad -> conflict-free transpose reads

    for (int e = t; e < 32 * 112; e += 256) {
        int cl = e / 112, ll = e % 112;
        float v = __builtin_nontemporal_load(
            x + (size_t)b * (C_IN * HW_) + (size_t)(c0 + cl) * HW_ + (l0 + ll));
        tile[cl][ll] = (_Float16)v;
    }
    __syncthreads();

    for (int e = t; e < 112 * 32; e += 256) {
        int ll = e >> 5, cl = e & 31;
        xp[(size_t)(l0 + ll) * (BS * C_IN) + b * C_IN + (c0 + cl)] = tile[cl][ll];
    }
}

// ---------------------------------------------------------------------------
// Kernel 1: per (location l, 256-wide d-chunk) GEMM  [64b x 256c] @ [256c x 256d]
// Permuted MFMA column mapping: instance n, col ln  <->  d = wave*64 + 4*ln + n.
// Lane's B frag = 8 k-rows x 4 contiguous d -> 8 coalesced NON-TEMPORAL dwordx4
// per k-step (W zero reuse -> bypass cache). fp32->fp16 via packed cvt_pkrtz.
// No W LDS, no K-loop barriers; 2-deep register prefetch.
// A (x, fp16) staged once in LDS (XOR-swizzled).
// patches stores CACHED (103 MB, consumed by next kernel -> keep in 256MB L3).
// ---------------------------------------------------------------------------
__global__ __launch_bounds__(256) void lc_gemm(const _Float16* __restrict__ xp,
                                               const float* __restrict__ W,
                                               _Float16* __restrict__ patches) {
    // XCD-aware swizzle: nwg = 3136 = 8 * 392; 4 chunks of one l stay on one XCD
    const int wg    = blockIdx.x;
    const int lcid  = (wg & 7) * 392 + (wg >> 3);
    const int l     = lcid >> 2;
    const int chunk = lcid & 3;

    const int t     = threadIdx.x;
    const int wave  = t >> 6;
    const int lane  = t & 63;
    const int g     = lane >> 4;      // 0..3  (k-group)
    const int ln    = lane & 15;      // row/col within fragment

    __shared__ __attribute__((aligned(16))) char lds[32 * 1024];

    // ---- stage A tile [64 b][256 c] fp16 (row = 512 B, XOR swizzle (row&7)<<4) ----
    {
        const int4v* src = (const int4v*)(xp + (size_t)l * (BS * C_IN));
        #pragma unroll
        for (int it = 0; it < 8; ++it) {
            int ch  = t + it * 256;        // 16B granule id, 0..2047
            int row = ch >> 5;
            int col = ch & 31;
            int4v v = src[ch];
            *(int4v*)(lds + row * 512 + ((col * 16) ^ ((row & 7) << 4))) = v;
        }
    }
    __syncthreads();

    // this thread's W base: k-row (g*8), d-quad (chunk*256 + wave*64 + 4*ln)
    const float* Wb = W + (size_t)l * (C_IN * D_TOT) + chunk * 256 + wave * 64 + 4 * ln;

    fl4 wA[8], wB[8];
    #pragma unroll
    for (int r = 0; r < 8; ++r)
        wA[r] = __builtin_nontemporal_load((const fl4*)(Wb + (size_t)(g * 8 + r) * D_TOT));
    #pragma unroll
    for (int r = 0; r < 8; ++r)
        wB[r] = __builtin_nontemporal_load((const fl4*)(Wb + (size_t)(32 + g * 8 + r) * D_TOT));

    f32x4 acc[4][4];
    #pragma unroll
    for (int m = 0; m < 4; ++m)
        #pragma unroll
        for (int n = 0; n < 4; ++n)
            acc[m][n] = (f32x4){0.f, 0.f, 0.f, 0.f};

    #pragma unroll
    for (int s = 0; s < 8; s += 2) {
        // ---------- even substep: consume wA (k0 = s*32), prefetch s+2 ----------
        {
            H8 bfr[4];
            #pragma unroll
            for (int n = 0; n < 4; ++n)
                #pragma unroll
                for (int j = 0; j < 4; ++j)
                    bfr[n].h2[j] = __builtin_amdgcn_cvt_pkrtz(wA[2 * j][n], wA[2 * j + 1][n]);

            if (s + 2 < 8) {
                #pragma unroll
                for (int r = 0; r < 8; ++r)
                    wA[r] = __builtin_nontemporal_load(
                        (const fl4*)(Wb + (size_t)((s + 2) * 32 + g * 8 + r) * D_TOT));
            }

            const int k0 = s * 32;
            half8 af[4];
            #pragma unroll
            for (int m = 0; m < 4; ++m) {
                int row = 16 * m + ln;
                af[m] = *(const half8*)(lds + row * 512 +
                                        ((((k0 + g * 8) << 1)) ^ ((row & 7) << 4)));
            }
            #pragma unroll
            for (int m = 0; m < 4; ++m)
                #pragma unroll
                for (int n = 0; n < 4; ++n)
                    acc[m][n] = __builtin_amdgcn_mfma_f32_16x16x32_f16(af[m], bfr[n].v,
                                                                       acc[m][n], 0, 0, 0);
        }
        // ---------- odd substep: consume wB (k0 = (s+1)*32), prefetch s+3 ----------
        {
            H8 bfr[4];
            #pragma unroll
            for (int n = 0; n < 4; ++n)
                #pragma unroll
                for (int j = 0; j < 4; ++j)
                    bfr[n].h2[j] = __builtin_amdgcn_cvt_pkrtz(wB[2 * j][n], wB[2 * j + 1][n]);

            if (s + 3 < 8) {
                #pragma unroll
                for (int r = 0; r < 8; ++r)
                    wB[r] = __builtin_nontemporal_load(
                        (const fl4*)(Wb + (size_t)((s + 3) * 32 + g * 8 + r) * D_TOT));
            }

            const int k0 = (s + 1) * 32;
            half8 af[4];
            #pragma unroll
            for (int m = 0; m < 4; ++m) {
                int row = 16 * m + ln;
                af[m] = *(const half8*)(lds + row * 512 +
                                        ((((k0 + g * 8) << 1)) ^ ((row & 7) << 4)));
            }
            #pragma unroll
            for (int m = 0; m < 4; ++m)
                #pragma unroll
                for (int n = 0; n < 4; ++n)
                    acc[m][n] = __builtin_amdgcn_mfma_f32_16x16x32_f16(af[m], bfr[n].v,
                                                                       acc[m][n], 0, 0, 0);
        }
    }

    // ---- epilogue: LDS transpose to fp16, then coalesced CACHED global stores ----
    __syncthreads();                       // all waves done reading A tile
    _Float16* hl = (_Float16*)lds;         // reuse: [64 b][256 d'] fp16 = 32 KB
    #pragma unroll
    for (int m = 0; m < 4; ++m) {
        #pragma unroll
        for (int r = 0; r < 4; ++r) {
            int b = 16 * m + 4 * g + r;
            half4 hq;
            #pragma unroll
            for (int n = 0; n < 4; ++n) hq[n] = (_Float16)acc[m][n][r];
            // col ln of MFMA n corresponds to d' = wave*64 + 4*ln + n
            *(half4*)(hl + b * 256 + wave * 64 + 4 * ln) = hq;
        }
    }
    __syncthreads();

    _Float16* dst = patches + (size_t)l * (BS * D_TOT) + chunk * 256;
    #pragma unroll
    for (int it = 0; it < 8; ++it) {
        int idx = t + it * 256;            // 16B granule id, 0..2047
        int row = idx >> 5;                // b
        int gg  = idx & 31;
        *(int4v*)(dst + (size_t)row * D_TOT + gg * 8) =
            *(const int4v*)(hl + row * 256 + gg * 8);
    }
}

// ---------------------------------------------------------------------------
// Kernel 2: fold (overlap-add) gather — no atomics, every patch read once.
// Block = (b, oh-group of 4). Thread = (oc = t>>2, ww = t&3) owns ow = ww*8..+7.
// patches reads CACHED (should be L3-resident). out stores NT.
// ---------------------------------------------------------------------------
__global__ __launch_bounds__(256) void fold_k(const _Float16* __restrict__ patches,
                                              float* __restrict__ out) {
    const int b   = blockIdx.x;     // 0..63
    const int oh0 = blockIdx.y * 4; // 0,4,...,28
    const int t   = threadIdx.x;
    const int oc  = t >> 2;
    const int ww  = t & 3;
    const int wb  = ww * 8;

    float acc[4][8];
    #pragma unroll
    for (int a = 0; a < 4; ++a)
        #pragma unroll
        for (int o = 0; o < 8; ++o) acc[a][o] = 0.f;

    const size_t pboc = (size_t)b * D_TOT + (size_t)oc * 16;

    #pragma unroll
    for (int a = 0; a < 4; ++a) {
        const int oh = oh0 + a;
        if (oh > 30) continue;             // uniform branch (oh0 wave-uniform)
        #pragma unroll
        for (int di = 0; di < 4; ++di) {
            const int r = oh - di;
            if (r < 0 || r >= 28) continue;
            #pragma unroll
            for (int k = 0; k < 11; ++k) {
                const int wp = wb - 3 + k;
                if (wp < 0 || wp >= 28) continue;
                const int l = r * 28 + wp;
                half4 v = *(const half4*)(patches + (size_t)l * (BS * D_TOT) + pboc + di * 4);
                #pragma unroll
                for (int dj = 0; dj < 4; ++dj) {
                    const int o = (k - 3) + dj;        // = wp + dj - wb, compile-time
                    if (o < 0 || o >= 8) continue;
                    if (wb + o <= 30)
                        acc[a][o] += (float)v[dj];
                }
            }
        }
    }

    #pragma unroll
    for (int a = 0; a < 4; ++a) {
        const int oh = oh0 + a;
        if (oh > 30) continue;
        float* op = out + (((size_t)b * OC_ + oc) * OH_ + oh) * OW_ + wb;
        #pragma unroll
        for (int o = 0; o < 8; ++o) {
            if (wb + o <= 30) __builtin_nontemporal_store(acc[a][o], op + o);
        }
    }
}

// ---------------------------------------------------------------------------
extern "C" void kernel_launch(void* const* d_in, const int* in_sizes, int n_in,
                              void* d_out, int out_size, void* d_ws, size_t ws_size,
                              hipStream_t stream) {
    const float* x = (const float*)d_in[0];
    const float* W = (const float*)d_in[1];
    float* out     = (float*)d_out;

    _Float16* xp      = (_Float16*)d_ws;                              // 25.7 MB
    _Float16* patches = (_Float16*)((char*)d_ws + 25690112);          // 102.8 MB

    pack_x<<<dim3(64, 8, 7), 256, 0, stream>>>(x, xp);
    lc_gemm<<<dim3(HW_ * 4), 256, 0, stream>>>(xp, W, patches);
    fold_k<<<dim3(64, 8), 256, 0, stream>>>(patches, out);
}